// Round 1
// baseline (578.411 us; speedup 1.0000x reference)
//
#include <hip/hip_runtime.h>

#define S_LEN 2048
#define HID 2048
#define NH 16
#define HD 128

typedef unsigned short ushort_t;
using bf16x8 = __attribute__((ext_vector_type(8))) __bf16;
using f32x4 = __attribute__((ext_vector_type(4))) float;
using ushort8 = __attribute__((ext_vector_type(8))) unsigned short;
using ushort4v = __attribute__((ext_vector_type(4))) unsigned short;

__device__ __forceinline__ unsigned short f2bf(float f) {
  unsigned int u = __float_as_uint(f);
  unsigned int r = u + 0x7FFFu + ((u >> 16) & 1u);
  return (unsigned short)(r >> 16);
}
__device__ __forceinline__ float bf2f(unsigned short h) {
  return __uint_as_float(((unsigned int)h) << 16);
}

__device__ __forceinline__ void gload_lds16(const ushort_t* g, ushort_t* lds) {
  __builtin_amdgcn_global_load_lds(
      (const __attribute__((address_space(1))) unsigned int*)g,
      (__attribute__((address_space(3))) unsigned int*)lds, 16, 0, 0);
}

// ---------------- cast fp32 -> bf16, 4 elems/thread ----------------
__global__ void cast_bf16_kernel(const float* __restrict__ in, ushort_t* __restrict__ out, int n4) {
  int i = blockIdx.x * 256 + threadIdx.x;
  if (i >= n4) return;
  float4 v = reinterpret_cast<const float4*>(in)[i];
  ushort4v o;
  o.x = f2bf(v.x); o.y = f2bf(v.y); o.z = f2bf(v.z); o.w = f2bf(v.w);
  reinterpret_cast<ushort4v*>(out)[i] = o;
}

// ---------------- RoPE cos/sin table [S][64] fp32 ----------------
__global__ void rope_table_kernel(float* __restrict__ cosT, float* __restrict__ sinT) {
  int i = blockIdx.x * 256 + threadIdx.x;
  if (i >= S_LEN * 64) return;
  int s = i >> 6, j = i & 63;
  // inv_freq = 10000^(-j/64) = exp(-j * ln(10000)/64)
  float inv = __expf(-(float)j * (9.210340371976184f / 64.0f));
  float ang = (float)s * inv;
  float sv, cv;
  sincosf(ang, &sv, &cv);
  cosT[i] = cv;
  sinT[i] = sv;
}

// ---------------- in-place RoPE (+ optional key_weights*scale fold) ----------------
__global__ void rope_apply_kernel(ushort_t* __restrict__ q, const float* __restrict__ cosT,
                                  const float* __restrict__ sinT, const float* __restrict__ kw,
                                  int rowLen, float scale, int useKw, int n) {
  int idx = blockIdx.x * 256 + threadIdx.x;
  if (idx >= n) return;
  int half = rowLen >> 1;
  int row = idx / half;
  int p = idx - row * half;
  int h = p >> 6, j = p & 63;
  int s = row & (S_LEN - 1);
  float c = cosT[(s << 6) + j];
  float sn = sinT[(s << 6) + j];
  long base = (long)row * rowLen + h * HD;
  float x1 = bf2f(q[base + j]);
  float x2 = bf2f(q[base + j + 64]);
  float wsc = useKw ? (scale * kw[h]) : scale;
  q[base + j] = f2bf((x1 * c - x2 * sn) * wsc);
  q[base + j + 64] = f2bf((x1 * sn + x2 * c) * wsc);
}

// ---------------- GEMM: C[M][N] = A[M][K] @ W[N][K]^T  (bf16 in, OT out) ----------------
__device__ __forceinline__ void store_c(ushort_t* p, float v) { *p = f2bf(v); }
__device__ __forceinline__ void store_c(float* p, float v) { *p = v; }

template <typename OT>
__global__ __launch_bounds__(256) void gemm_bt_kernel(const ushort_t* __restrict__ A,
                                                      const ushort_t* __restrict__ W,
                                                      OT* __restrict__ C, int M, int N, int K) {
  __shared__ ushort_t As[128 * 32];
  __shared__ ushort_t Bs[128 * 32];
  const int tid = threadIdx.x;
  const int l = tid & 63, w = tid >> 6;
  const int wr = w >> 1, wc = w & 1;
  const int r = l & 15, g = l >> 4;
  const long arow0 = (long)blockIdx.y * 128;
  const long brow0 = (long)blockIdx.x * 128;

  f32x4 acc[4][4] = {};

  const int c0 = tid, c1 = tid + 256;
  const ushort_t* a_src0 = A + (arow0 + (c0 >> 2)) * K + ((c0 & 3) << 3);
  const ushort_t* a_src1 = A + (arow0 + (c1 >> 2)) * K + ((c1 & 3) << 3);
  const ushort_t* b_src0 = W + (brow0 + (c0 >> 2)) * K + ((c0 & 3) << 3);
  const ushort_t* b_src1 = W + (brow0 + (c1 >> 2)) * K + ((c1 & 3) << 3);
  ushort_t* a_dst0 = &As[c0 * 8];
  ushort_t* a_dst1 = &As[c1 * 8];
  ushort_t* b_dst0 = &Bs[c0 * 8];
  ushort_t* b_dst1 = &Bs[c1 * 8];

  for (int kk = 0; kk < K; kk += 32) {
    gload_lds16(a_src0 + kk, a_dst0);
    gload_lds16(a_src1 + kk, a_dst1);
    gload_lds16(b_src0 + kk, b_dst0);
    gload_lds16(b_src1 + kk, b_dst1);
    __syncthreads();
    bf16x8 af[4], bw[4];
#pragma unroll
    for (int mi = 0; mi < 4; ++mi)
      af[mi] = *reinterpret_cast<const bf16x8*>(&As[(wr * 64 + mi * 16 + r) * 32 + g * 8]);
#pragma unroll
    for (int ni = 0; ni < 4; ++ni)
      bw[ni] = *reinterpret_cast<const bf16x8*>(&Bs[(wc * 64 + ni * 16 + r) * 32 + g * 8]);
#pragma unroll
    for (int mi = 0; mi < 4; ++mi)
#pragma unroll
      for (int ni = 0; ni < 4; ++ni)
        acc[mi][ni] = __builtin_amdgcn_mfma_f32_16x16x32_bf16(af[mi], bw[ni], acc[mi][ni], 0, 0, 0);
    __syncthreads();
  }

#pragma unroll
  for (int mi = 0; mi < 4; ++mi)
#pragma unroll
    for (int ni = 0; ni < 4; ++ni) {
      int col = (int)brow0 + wc * 64 + ni * 16 + r;
#pragma unroll
      for (int j = 0; j < 4; ++j) {
        int row = (int)arow0 + wr * 64 + mi * 16 + g * 4 + j;
        store_c(&C[(long)row * N + col], acc[mi][ni][j]);
      }
    }
}

// ---------------- causal GQA flash attention ----------------
// grid: (S/128) * NH * B blocks of 256 threads. Each wave owns 32 q rows.
// Q: [B*S][2048] (rope'd, *kw*scale), K/V: [B*S][512] (K rope'd), AO out: [B*S][2048]
__global__ __launch_bounds__(256) void flash_attn_kernel(const ushort_t* __restrict__ Q,
                                                         const ushort_t* __restrict__ Kt,
                                                         const ushort_t* __restrict__ Vt,
                                                         ushort_t* __restrict__ AO) {
  __shared__ ushort_t Ks[64 * 128];      // xor-swizzled via pre-swizzled source
  __shared__ ushort_t Vts[128 * 72];     // transposed [d][key], key-block xor swizzle
  __shared__ ushort_t Ps[4][32 * 72];    // per-wave P round-trip, padded

  const int bid = blockIdx.x;
  const int qt = bid & 15;
  const int h = (bid >> 4) & 15;
  const int b = bid >> 8;
  const int tid = threadIdx.x;
  const int l = tid & 63, w = tid >> 6;
  const int r = l & 15, g = l >> 4;
  const int kvh = h >> 2;
  const long qrow0 = (long)b * S_LEN + qt * 128 + w * 32;
  const int qg = qt * 128 + w * 32;

  // Q fragments in registers: rows mi*16+r, k = ks*32+g*8..+7
  bf16x8 qa[2][4];
#pragma unroll
  for (int mi = 0; mi < 2; ++mi)
#pragma unroll
    for (int ks = 0; ks < 4; ++ks)
      qa[mi][ks] = *reinterpret_cast<const bf16x8*>(
          Q + (qrow0 + mi * 16 + r) * HID + h * HD + ks * 32 + g * 8);

  f32x4 acc[2][8] = {};
  float mrow[2][4], lrow[2][4];
#pragma unroll
  for (int mi = 0; mi < 2; ++mi)
#pragma unroll
    for (int j = 0; j < 4; ++j) { mrow[mi][j] = -1e30f; lrow[mi][j] = 0.f; }

  const ushort_t* Kb = Kt + (long)b * S_LEN * 512 + kvh * HD;
  const ushort_t* Vb = Vt + (long)b * S_LEN * 512 + kvh * HD;
  const int nkv = 2 * qt + 2;

  for (int kv = 0; kv < nkv; ++kv) {
    __syncthreads();  // prior tile fully consumed before overwrite
    // ---- stage K (source pre-swizzled so swizzled reads are conflict-light)
#pragma unroll
    for (int i = 0; i < 4; ++i) {
      int c = tid + i * 256;
      int krow = c >> 4, cc = c & 15;
      int scc = cc ^ (krow & 7);
      gload_lds16(Kb + (long)(kv * 64 + krow) * 512 + scc * 8, &Ks[c * 8]);
    }
    // ---- stage V transposed via registers
#pragma unroll
    for (int i = 0; i < 4; ++i) {
      int c = tid + i * 256;
      int key = c >> 4;
      int d0 = (c & 15) * 8;
      ushort8 v8 = *reinterpret_cast<const ushort8*>(Vb + (long)(kv * 64 + key) * 512 + d0);
      int kb8 = key >> 3, kj = key & 7;
#pragma unroll
      for (int e = 0; e < 8; ++e) {
        int d = d0 + e;
        Vts[d * 72 + ((kb8 ^ ((d >> 3) & 7)) << 3) + kj] = v8[e];
      }
    }
    __syncthreads();

    if (kv * 64 > qg + 31) continue;  // tile fully masked for this wave

    // ---- S = Q @ K^T
    f32x4 s[2][4] = {};
#pragma unroll
    for (int ks = 0; ks < 4; ++ks) {
      bf16x8 kf[4];
#pragma unroll
      for (int ni = 0; ni < 4; ++ni) {
        int n = ni * 16 + r;
        int colByte = ks * 64 + g * 16;
        int sw = colByte ^ ((n & 7) << 4);
        kf[ni] = *reinterpret_cast<const bf16x8*>(reinterpret_cast<const char*>(Ks) + n * 256 + sw);
      }
#pragma unroll
      for (int mi = 0; mi < 2; ++mi)
#pragma unroll
        for (int ni = 0; ni < 4; ++ni)
          s[mi][ni] = __builtin_amdgcn_mfma_f32_16x16x32_bf16(qa[mi][ks], kf[ni], s[mi][ni], 0, 0, 0);
    }
    // ---- causal mask (diagonal tiles only)
    if (kv * 64 + 63 > qg) {
#pragma unroll
      for (int mi = 0; mi < 2; ++mi)
#pragma unroll
        for (int ni = 0; ni < 4; ++ni) {
          int key = kv * 64 + ni * 16 + r;
#pragma unroll
          for (int j = 0; j < 4; ++j) {
            int rowq = qg + mi * 16 + g * 4 + j;
            if (key > rowq) s[mi][ni][j] = -1e30f;
          }
        }
    }
    // ---- online softmax (max reduced over 16-lane group; sum deferred)
#pragma unroll
    for (int mi = 0; mi < 2; ++mi) {
#pragma unroll
      for (int j = 0; j < 4; ++j) {
        float mx = fmaxf(fmaxf(s[mi][0][j], s[mi][1][j]), fmaxf(s[mi][2][j], s[mi][3][j]));
        mx = fmaxf(mx, __shfl_xor(mx, 1));
        mx = fmaxf(mx, __shfl_xor(mx, 2));
        mx = fmaxf(mx, __shfl_xor(mx, 4));
        mx = fmaxf(mx, __shfl_xor(mx, 8));
        float mo = mrow[mi][j];
        float mn = fmaxf(mo, mx);
        float ef = __expf(mo - mn);
        mrow[mi][j] = mn;
        float psum = 0.f;
#pragma unroll
        for (int ni = 0; ni < 4; ++ni) {
          float p = __expf(s[mi][ni][j] - mn);
          s[mi][ni][j] = p;
          psum += p;
        }
        lrow[mi][j] = lrow[mi][j] * ef + psum;
#pragma unroll
        for (int ni = 0; ni < 8; ++ni) acc[mi][ni][j] *= ef;
      }
    }
    // ---- P -> per-wave LDS (C layout -> A-fragment layout)
#pragma unroll
    for (int mi = 0; mi < 2; ++mi)
#pragma unroll
      for (int ni = 0; ni < 4; ++ni)
#pragma unroll
        for (int j = 0; j < 4; ++j)
          Ps[w][(mi * 16 + g * 4 + j) * 72 + ni * 16 + r] = f2bf(s[mi][ni][j]);
    // ---- O += P @ V
#pragma unroll
    for (int ks2 = 0; ks2 < 2; ++ks2) {
      bf16x8 pa[2];
#pragma unroll
      for (int mi = 0; mi < 2; ++mi)
        pa[mi] = *reinterpret_cast<const bf16x8*>(&Ps[w][(mi * 16 + r) * 72 + ks2 * 32 + g * 8]);
#pragma unroll
      for (int ni = 0; ni < 8; ++ni) {
        int d = ni * 16 + r;
        int kb8 = ks2 * 4 + g;
        bf16x8 vf = *reinterpret_cast<const bf16x8*>(&Vts[d * 72 + ((kb8 ^ ((d >> 3) & 7)) << 3)]);
#pragma unroll
        for (int mi = 0; mi < 2; ++mi)
          acc[mi][ni] = __builtin_amdgcn_mfma_f32_16x16x32_bf16(pa[mi], vf, acc[mi][ni], 0, 0, 0);
      }
    }
  }

  // ---- epilogue: finish row sums, normalize, write AO
#pragma unroll
  for (int mi = 0; mi < 2; ++mi)
#pragma unroll
    for (int j = 0; j < 4; ++j) {
      float lt = lrow[mi][j];
      lt += __shfl_xor(lt, 1);
      lt += __shfl_xor(lt, 2);
      lt += __shfl_xor(lt, 4);
      lt += __shfl_xor(lt, 8);
      float inv = 1.0f / lt;
#pragma unroll
      for (int ni = 0; ni < 8; ++ni) acc[mi][ni][j] *= inv;
    }
#pragma unroll
  for (int mi = 0; mi < 2; ++mi)
#pragma unroll
    for (int ni = 0; ni < 8; ++ni) {
      int col = h * HD + ni * 16 + r;
#pragma unroll
      for (int j = 0; j < 4; ++j) {
        long row = qrow0 + mi * 16 + g * 4 + j;
        AO[row * HID + col] = f2bf(acc[mi][ni][j]);
      }
    }
}

// ---------------- host launch ----------------
extern "C" void kernel_launch(void* const* d_in, const int* in_sizes, int n_in,
                              void* d_out, int out_size, void* d_ws, size_t ws_size,
                              hipStream_t stream) {
  const float* x = (const float*)d_in[0];
  const float* wq = (const float*)d_in[1];
  const float* wk = (const float*)d_in[2];
  const float* wv = (const float*)d_in[3];
  const float* wo = (const float*)d_in[4];
  const float* kw = (const float*)d_in[5];
  float* out = (float*)d_out;

  ushort_t* ws = (ushort_t*)d_ws;
  ushort_t* xb = ws;                 // 4096x2048 bf16; reused as attention output
  ushort_t* qb = xb + 8388608;       // 4096x2048
  ushort_t* kb = qb + 8388608;       // 4096x512
  ushort_t* vb = kb + 2097152;       // 4096x512
  ushort_t* wqb = vb + 2097152;      // 2048x2048
  ushort_t* wkb = wqb + 4194304;     // 512x2048
  ushort_t* wvb = wkb + 1048576;     // 512x2048
  ushort_t* wob = wvb + 1048576;     // 2048x2048
  float* cosT = (float*)(wob + 4194304);
  float* sinT = cosT + S_LEN * 64;

  cast_bf16_kernel<<<8192, 256, 0, stream>>>(x, xb, 2097152);
  cast_bf16_kernel<<<4096, 256, 0, stream>>>(wq, wqb, 1048576);
  cast_bf16_kernel<<<1024, 256, 0, stream>>>(wk, wkb, 262144);
  cast_bf16_kernel<<<1024, 256, 0, stream>>>(wv, wvb, 262144);
  cast_bf16_kernel<<<4096, 256, 0, stream>>>(wo, wob, 1048576);
  rope_table_kernel<<<512, 256, 0, stream>>>(cosT, sinT);

  gemm_bt_kernel<ushort_t><<<dim3(16, 32), 256, 0, stream>>>(xb, wqb, qb, 4096, 2048, 2048);
  gemm_bt_kernel<ushort_t><<<dim3(4, 32), 256, 0, stream>>>(xb, wkb, kb, 4096, 512, 2048);
  gemm_bt_kernel<ushort_t><<<dim3(4, 32), 256, 0, stream>>>(xb, wvb, vb, 4096, 512, 2048);

  // fold key_weights * D^-0.5 into Q (scores = (q*w*s)·k)
  rope_apply_kernel<<<16384, 256, 0, stream>>>(qb, cosT, sinT, kw, 2048,
                                               0.08838834764831845f, 1, 4194304);
  rope_apply_kernel<<<4096, 256, 0, stream>>>(kb, cosT, sinT, kw, 512, 1.0f, 0, 1048576);

  flash_attn_kernel<<<512, 256, 0, stream>>>(qb, kb, vb, xb);

  gemm_bt_kernel<float><<<dim3(16, 32), 256, 0, stream>>>(xb, wob, out, 4096, 2048, 2048);
}

// Round 4
// 349.432 us; speedup vs baseline: 1.6553x; 1.6553x over previous
//
#include <hip/hip_runtime.h>

#define S_LEN 2048
#define HID 2048
#define NH 16
#define HD 128
#define QKV_N 3072   // 2048 q + 512 k + 512 v
#define KCOL 2048
#define VCOL 2560

typedef unsigned short ushort_t;
using bf16x8 = __attribute__((ext_vector_type(8))) __bf16;
using f32x4 = __attribute__((ext_vector_type(4))) float;
using ushort8 = __attribute__((ext_vector_type(8))) unsigned short;
using ushort4v = __attribute__((ext_vector_type(4))) unsigned short;

__device__ __forceinline__ unsigned short f2bf(float f) {
  unsigned int u = __float_as_uint(f);
  unsigned int r = u + 0x7FFFu + ((u >> 16) & 1u);
  return (unsigned short)(r >> 16);
}
__device__ __forceinline__ float bf2f(unsigned short h) {
  return __uint_as_float(((unsigned int)h) << 16);
}

__device__ __forceinline__ void gload_lds16(const ushort_t* g, ushort_t* lds) {
  __builtin_amdgcn_global_load_lds(
      (const __attribute__((address_space(1))) unsigned int*)g,
      (__attribute__((address_space(3))) unsigned int*)lds, 16, 0, 0);
}

// ---------------- cast fp32 -> bf16, 4 elems/thread ----------------
__global__ void cast_bf16_kernel(const float* __restrict__ in, ushort_t* __restrict__ out, int n4) {
  int i = blockIdx.x * 256 + threadIdx.x;
  if (i >= n4) return;
  float4 v = reinterpret_cast<const float4*>(in)[i];
  ushort4v o;
  o.x = f2bf(v.x); o.y = f2bf(v.y); o.z = f2bf(v.z); o.w = f2bf(v.w);
  reinterpret_cast<ushort4v*>(out)[i] = o;
}

// ---------------- RoPE cos/sin table [S][64] fp32 ----------------
__global__ void rope_table_kernel(float* __restrict__ cosT, float* __restrict__ sinT) {
  int i = blockIdx.x * 256 + threadIdx.x;
  if (i >= S_LEN * 64) return;
  int s = i >> 6, j = i & 63;
  float inv = __expf(-(float)j * (9.210340371976184f / 64.0f));
  float ang = (float)s * inv;
  float sv, cv;
  sincosf(ang, &sv, &cv);
  cosT[i] = cv;
  sinT[i] = sv;
}

// ---------------- in-place RoPE on a column-region of qkv ----------------
__global__ void rope_apply_kernel(ushort_t* __restrict__ base, const float* __restrict__ cosT,
                                  const float* __restrict__ sinT, const float* __restrict__ kw,
                                  int stride, int lognh, float scale, int useKw, int n) {
  int idx = blockIdx.x * 256 + threadIdx.x;
  if (idx >= n) return;
  int row = idx >> lognh;
  int p = idx & ((1 << lognh) - 1);
  int h = p >> 6, j = p & 63;
  int s = row & (S_LEN - 1);
  float c = cosT[(s << 6) + j];
  float sn = sinT[(s << 6) + j];
  long a = (long)row * stride + h * HD;
  float x1 = bf2f(base[a + j]);
  float x2 = bf2f(base[a + j + 64]);
  float wsc = useKw ? (scale * kw[h]) : scale;
  base[a + j] = f2bf((x1 * c - x2 * sn) * wsc);
  base[a + j + 64] = f2bf((x1 * sn + x2 * c) * wsc);
}

// ---------------- V transpose: qkv V-region [4096][512] -> vt[b*512+vd][2048] ----------------
__global__ __launch_bounds__(256) void transpose_v_kernel(const ushort_t* __restrict__ qkv,
                                                          ushort_t* __restrict__ vt) {
  __shared__ ushort_t T[64][76];
  int bid = blockIdx.x;  // 512 = 64 token-tiles x 8 dim-tiles
  int dd = bid & 7;
  int tt = bid >> 3;
  int tid = threadIdx.x;
#pragma unroll
  for (int it = 0; it < 2; ++it) {
    int c = tid + it * 256;
    int i = c >> 3, j8 = c & 7;
    ushort8 v = *reinterpret_cast<const ushort8*>(
        qkv + (long)(tt * 64 + i) * QKV_N + VCOL + dd * 64 + j8 * 8);
    *reinterpret_cast<ushort8*>(&T[i][j8 * 8]) = v;
  }
  __syncthreads();
#pragma unroll
  for (int it = 0; it < 2; ++it) {
    int c = tid + it * 256;
    int jd = c >> 3, sc = c & 7;
    ushort8 o;
#pragma unroll
    for (int e = 0; e < 8; ++e) o[e] = T[sc * 8 + e][jd];
    int token = tt * 64 + sc * 8;
    int b = token >> 11, s = token & (S_LEN - 1);
    int vd = dd * 64 + jd;
    *reinterpret_cast<ushort8*>(vt + ((long)(b * 512 + vd) << 11) + s) = o;
  }
}

// ---------------- GEMM: C[M][N] = A[M][K] @ W[N][K]^T ----------------
__device__ __forceinline__ void store_c(ushort_t* p, float v) { *p = f2bf(v); }
__device__ __forceinline__ void store_c(float* p, float v) { *p = v; }

template <typename OT>
__global__ __launch_bounds__(256) void gemm_bt_kernel(const ushort_t* __restrict__ A,
                                                      const ushort_t* __restrict__ W,
                                                      OT* __restrict__ C, int M, int N, int K) {
  __shared__ ushort_t As[128 * 32];
  __shared__ ushort_t Bs[128 * 32];
  const int tid = threadIdx.x;
  const int l = tid & 63, w = tid >> 6;
  const int wr = w >> 1, wc = w & 1;
  const int r = l & 15, g = l >> 4;
  const long arow0 = (long)blockIdx.y * 128;
  const long brow0 = (long)blockIdx.x * 128;

  f32x4 acc[4][4] = {};

  const int c0 = tid, c1 = tid + 256;
  const ushort_t* a_src0 = A + (arow0 + (c0 >> 2)) * K + ((c0 & 3) << 3);
  const ushort_t* a_src1 = A + (arow0 + (c1 >> 2)) * K + ((c1 & 3) << 3);
  const ushort_t* b_src0 = W + (brow0 + (c0 >> 2)) * K + ((c0 & 3) << 3);
  const ushort_t* b_src1 = W + (brow0 + (c1 >> 2)) * K + ((c1 & 3) << 3);
  ushort_t* a_dst0 = &As[c0 * 8];
  ushort_t* a_dst1 = &As[c1 * 8];
  ushort_t* b_dst0 = &Bs[c0 * 8];
  ushort_t* b_dst1 = &Bs[c1 * 8];

  for (int kk = 0; kk < K; kk += 32) {
    gload_lds16(a_src0 + kk, a_dst0);
    gload_lds16(a_src1 + kk, a_dst1);
    gload_lds16(b_src0 + kk, b_dst0);
    gload_lds16(b_src1 + kk, b_dst1);
    __syncthreads();
    bf16x8 af[4], bw[4];
#pragma unroll
    for (int mi = 0; mi < 4; ++mi)
      af[mi] = *reinterpret_cast<const bf16x8*>(&As[(wr * 64 + mi * 16 + r) * 32 + g * 8]);
#pragma unroll
    for (int ni = 0; ni < 4; ++ni)
      bw[ni] = *reinterpret_cast<const bf16x8*>(&Bs[(wc * 64 + ni * 16 + r) * 32 + g * 8]);
#pragma unroll
    for (int mi = 0; mi < 4; ++mi)
#pragma unroll
      for (int ni = 0; ni < 4; ++ni)
        acc[mi][ni] = __builtin_amdgcn_mfma_f32_16x16x32_bf16(af[mi], bw[ni], acc[mi][ni], 0, 0, 0);
    __syncthreads();
  }

#pragma unroll
  for (int mi = 0; mi < 4; ++mi)
#pragma unroll
    for (int ni = 0; ni < 4; ++ni) {
      int col = (int)brow0 + wc * 64 + ni * 16 + r;
#pragma unroll
      for (int j = 0; j < 4; ++j) {
        int row = (int)arow0 + wr * 64 + mi * 16 + g * 4 + j;
        store_c(&C[(long)row * N + col], acc[mi][ni][j]);
      }
    }
}

// ---------------- causal GQA flash attention (pair-balanced) ----------------
// 512 blocks: pair (bid&15), h, b. Block does q-tiles {qt, 31-qt} of 64 rows.
// 4 waves x 16 q-rows. Q/K read from qkv (stride 3072); V from vt (d-major).
__global__ __launch_bounds__(256) void flash_attn_kernel(const ushort_t* __restrict__ qkv,
                                                         const ushort_t* __restrict__ Vt,
                                                         ushort_t* __restrict__ AO) {
  __shared__ ushort_t Ks[64 * 128];   // [key][d], source pre-swizzled per 16B chunk
  __shared__ ushort_t Vts[128 * 64];  // [d][key], source pre-swizzled per 16B chunk
  __shared__ ushort_t Ps[4][16 * 68];

  const int bid = blockIdx.x;
  const int pr = bid & 15;
  const int h = (bid >> 4) & 15;
  const int b = bid >> 8;
  const int tid = threadIdx.x;
  const int l = tid & 63, w = tid >> 6;
  const int r = l & 15, g = l >> 4;
  const int kvh = h >> 2;

  const ushort_t* Qb = qkv + (long)b * S_LEN * QKV_N + h * HD;     // batch-offset base
  const ushort_t* Kb = qkv + (long)b * S_LEN * QKV_N + KCOL + kvh * HD;
  const ushort_t* Vb = Vt + ((long)(b * 512 + kvh * HD) << 11);

  for (int pi = 0; pi < 2; ++pi) {
    const int qt = pi ? (31 - pr) : pr;
    const int qg = qt * 64 + w * 16;          // wave's first q row (batch-local)
    const long qrow0 = (long)b * S_LEN + qg;  // global token row (for AO write only)

    bf16x8 qa[4];
#pragma unroll
    for (int ks = 0; ks < 4; ++ks)   // FIX: batch-LOCAL row against batch-offset Qb
      qa[ks] = *reinterpret_cast<const bf16x8*>(Qb + (long)(qg + r) * QKV_N + ks * 32 + g * 8);

    f32x4 acc[8] = {};
    float mrow[4], lrow[4];
#pragma unroll
    for (int j = 0; j < 4; ++j) { mrow[j] = -1e30f; lrow[j] = 0.f; }

    for (int kv = 0; kv <= qt; ++kv) {
      __syncthreads();  // prior tile fully consumed
      // ---- stage K [64 keys][128 d]: 1024 16B chunks
#pragma unroll
      for (int i = 0; i < 4; ++i) {
        int c = tid + i * 256;
        int krow = c >> 4, cc = c & 15;
        int scc = cc ^ (krow & 7);
        gload_lds16(Kb + (long)(kv * 64 + krow) * QKV_N + scc * 8, &Ks[c * 8]);
      }
      // ---- stage V^T [128 d][64 keys]: 1024 16B chunks
#pragma unroll
      for (int i = 0; i < 4; ++i) {
        int c = tid + i * 256;
        int vrow = c >> 3, cc = c & 7;
        int scc = cc ^ (vrow & 7);
        gload_lds16(Vb + ((long)vrow << 11) + kv * 64 + scc * 8, &Vts[c * 8]);
      }
      __syncthreads();

      // ---- S = Q @ K^T
      f32x4 s[4] = {};
#pragma unroll
      for (int ks = 0; ks < 4; ++ks) {
        bf16x8 kf[4];
#pragma unroll
        for (int ni = 0; ni < 4; ++ni) {
          int n = ni * 16 + r;
          int chunk = (ks * 4 + g) ^ (n & 7);
          kf[ni] = *reinterpret_cast<const bf16x8*>(
              reinterpret_cast<const char*>(Ks) + n * 256 + chunk * 16);
        }
#pragma unroll
        for (int ni = 0; ni < 4; ++ni)
          s[ni] = __builtin_amdgcn_mfma_f32_16x16x32_bf16(qa[ks], kf[ni], s[ni], 0, 0, 0);
      }
      // ---- causal mask on diagonal tile
      if (kv == qt) {
#pragma unroll
        for (int ni = 0; ni < 4; ++ni) {
          int key = kv * 64 + ni * 16 + r;
#pragma unroll
          for (int j = 0; j < 4; ++j) {
            int rowq = qg + g * 4 + j;
            if (key > rowq) s[ni][j] = -1e30f;
          }
        }
      }
      // ---- online softmax
#pragma unroll
      for (int j = 0; j < 4; ++j) {
        float mx = fmaxf(fmaxf(s[0][j], s[1][j]), fmaxf(s[2][j], s[3][j]));
        mx = fmaxf(mx, __shfl_xor(mx, 1));
        mx = fmaxf(mx, __shfl_xor(mx, 2));
        mx = fmaxf(mx, __shfl_xor(mx, 4));
        mx = fmaxf(mx, __shfl_xor(mx, 8));
        float mo = mrow[j];
        float mn = fmaxf(mo, mx);
        float ef = __expf(mo - mn);
        mrow[j] = mn;
        float psum = 0.f;
#pragma unroll
        for (int ni = 0; ni < 4; ++ni) {
          float p = __expf(s[ni][j] - mn);
          s[ni][j] = p;
          psum += p;
        }
        lrow[j] = lrow[j] * ef + psum;
#pragma unroll
        for (int ni = 0; ni < 8; ++ni) acc[ni][j] *= ef;
      }
      // ---- P -> per-wave LDS (C layout -> A-fragment layout)
#pragma unroll
      for (int ni = 0; ni < 4; ++ni)
#pragma unroll
        for (int j = 0; j < 4; ++j)
          Ps[w][(g * 4 + j) * 68 + ni * 16 + r] = f2bf(s[ni][j]);
      // ---- O += P @ V
#pragma unroll
      for (int ks2 = 0; ks2 < 2; ++ks2) {
        bf16x8 pa = *reinterpret_cast<const bf16x8*>(&Ps[w][r * 68 + ks2 * 32 + g * 8]);
#pragma unroll
        for (int ni = 0; ni < 8; ++ni) {
          int d = ni * 16 + r;
          int chunk = (ks2 * 4 + g) ^ (d & 7);
          bf16x8 vf = *reinterpret_cast<const bf16x8*>(
              reinterpret_cast<const char*>(Vts) + d * 128 + chunk * 16);
          acc[ni] = __builtin_amdgcn_mfma_f32_16x16x32_bf16(pa, vf, acc[ni], 0, 0, 0);
        }
      }
    }

    // ---- epilogue for this q-tile
#pragma unroll
    for (int j = 0; j < 4; ++j) {
      float lt = lrow[j];
      lt += __shfl_xor(lt, 1);
      lt += __shfl_xor(lt, 2);
      lt += __shfl_xor(lt, 4);
      lt += __shfl_xor(lt, 8);
      float inv = 1.0f / lt;
#pragma unroll
      for (int ni = 0; ni < 8; ++ni) acc[ni][j] *= inv;
    }
#pragma unroll
    for (int ni = 0; ni < 8; ++ni) {
      int col = h * HD + ni * 16 + r;
#pragma unroll
      for (int j = 0; j < 4; ++j) {
        long row = qrow0 + g * 4 + j;
        AO[row * HID + col] = f2bf(acc[ni][j]);
      }
    }
    __syncthreads();  // before second tile re-stages LDS
  }
}

// ---------------- host launch ----------------
extern "C" void kernel_launch(void* const* d_in, const int* in_sizes, int n_in,
                              void* d_out, int out_size, void* d_ws, size_t ws_size,
                              hipStream_t stream) {
  const float* x = (const float*)d_in[0];
  const float* wq = (const float*)d_in[1];
  const float* wk = (const float*)d_in[2];
  const float* wv = (const float*)d_in[3];
  const float* wo = (const float*)d_in[4];
  const float* kw = (const float*)d_in[5];
  float* out = (float*)d_out;

  ushort_t* ws = (ushort_t*)d_ws;
  ushort_t* xb = ws;                       // 4096x2048 bf16; reused as AO
  ushort_t* qkv = xb + 8388608;            // 4096x3072
  ushort_t* vt = qkv + 12582912;           // 1024x2048 (B*512 rows x 2048)
  ushort_t* wqkv = vt + 2097152;           // 3072x2048; later reused for wob
  float* cosT = (float*)(wqkv + 6291456);
  float* sinT = cosT + S_LEN * 64;

  cast_bf16_kernel<<<8192, 256, 0, stream>>>(x, xb, 2097152);
  cast_bf16_kernel<<<4096, 256, 0, stream>>>(wq, wqkv, 1048576);
  cast_bf16_kernel<<<1024, 256, 0, stream>>>(wk, wqkv + 2048 * 2048, 262144);
  cast_bf16_kernel<<<1024, 256, 0, stream>>>(wv, wqkv + 2560 * 2048, 262144);
  rope_table_kernel<<<512, 256, 0, stream>>>(cosT, sinT);

  // fused QKV projection: [4096][3072]
  gemm_bt_kernel<ushort_t><<<dim3(24, 32), 256, 0, stream>>>(xb, wqkv, qkv, 4096, QKV_N, 2048);

  // RoPE: q cols 0..2047 (fold kw*scale), k cols 2048..2559
  rope_apply_kernel<<<16384, 256, 0, stream>>>(qkv, cosT, sinT, kw, QKV_N, 10,
                                               0.08838834764831845f, 1, 4194304);
  rope_apply_kernel<<<4096, 256, 0, stream>>>(qkv + KCOL, cosT, sinT, kw, QKV_N, 8,
                                              1.0f, 0, 1048576);

  transpose_v_kernel<<<512, 256, 0, stream>>>(qkv, vt);

  // wo cast reuses wqkv region (qkv GEMM is done by stream order)
  ushort_t* wob = wqkv;
  cast_bf16_kernel<<<4096, 256, 0, stream>>>(wo, wob, 1048576);

  flash_attn_kernel<<<512, 256, 0, stream>>>(qkv, vt, xb);

  gemm_bt_kernel<float><<<dim3(16, 32), 256, 0, stream>>>(xb, wob, out, 4096, 2048, 2048);
}